// Round 1
// baseline (112.216 us; speedup 1.0000x reference)
//
#include <hip/hip_runtime.h>
#include <math.h>

// LinkedFocalLoss: mean_n [ w_n * (1-pt_n)^2 * ce_n ]
//   ce = -log_softmax(y_pred)[y_true], pt = exp(-ce), pred = argmax(y_pred)
//   w = 0.25 if (pred != gt && has_link[gt] && link_matrix[gt,pred]) else 1
// N=131072 rows, C=1000. HBM-bound on the single read of y_pred (524 MB).

#define NROWS 131072
#define NC 1000
#define NF4 250               // NC/4 float4 per row (4000 B, 16B aligned)
#define ROWS_PER_BLOCK 16     // 4 waves * 4 rows each
#define NBLOCKS (NROWS / ROWS_PER_BLOCK)  // 8192
#define ALPHA_LINK 0.25f

// ---- format detection -------------------------------------------------------
// flags[0] = 1 if y_true is stored as int64 (read low word at 2*row), else int32
// flags[1] = 1 if link_matrix/has_link stored as 1-byte bools, else int32
__global__ void lfl_detect(const int* __restrict__ yt,
                           const unsigned int* __restrict__ hl,
                           int* __restrict__ flags) {
    if (threadIdx.x == 0 && blockIdx.x == 0) {
        int y64 = 1;
        for (int i = 0; i < 64; ++i)
            if (yt[2 * i + 1] != 0) { y64 = 0; break; }   // int64 hi-words are 0
        int bfmt = 0;
        for (int i = 0; i < 250; ++i)
            if (hl[i] > 1u) { bfmt = 1; break; }          // bool bytes pack >1
        flags[0] = y64;
        flags[1] = bfmt;
    }
}

// ---- main: one wave per row -------------------------------------------------
__global__ __launch_bounds__(256) void lfl_main(
    const float* __restrict__ yp,
    const int* __restrict__ yt,
    const unsigned char* __restrict__ linkb, const int* __restrict__ linki,
    const unsigned char* __restrict__ hasb,  const int* __restrict__ hasi,
    const int* __restrict__ flags,
    float* __restrict__ partial)
{
    const int lane = threadIdx.x & 63;
    const int wid  = threadIdx.x >> 6;
    const int y64  = flags[0];
    const int bfmt = flags[1];

    float wsum = 0.0f;

    for (int r = 0; r < 4; ++r) {
        const int row = blockIdx.x * ROWS_PER_BLOCK + wid * 4 + r;
        const float4* rowp = (const float4*)(yp + (size_t)row * NC);
        const int target = y64 ? yt[2 * row] : yt[row];
        const int tf = target >> 2;      // float4 index holding the target logit

        // --- load: lane handles float4 indices lane, lane+64, lane+128, lane+192
        float4 v[4];
        v[0] = rowp[lane];
        v[1] = rowp[lane + 64];
        v[2] = rowp[lane + 128];
        const bool has3 = (lane + 192) < NF4;   // lanes 0..57
        v[3] = has3 ? rowp[lane + 192]
                    : make_float4(-INFINITY, -INFINITY, -INFINITY, -INFINITY);

        // --- local max + argmax (first occurrence wins) + target capture
        float lmax = -INFINITY;
        int   lidx = 1 << 30;
        float xt = 0.0f;
        #pragma unroll
        for (int k = 0; k < 4; ++k) {
            const int f  = lane + 64 * k;
            const int c0 = f * 4;
            const float x0 = v[k].x, x1 = v[k].y, x2 = v[k].z, x3 = v[k].w;
            if (x0 > lmax) { lmax = x0; lidx = c0; }
            if (x1 > lmax) { lmax = x1; lidx = c0 + 1; }
            if (x2 > lmax) { lmax = x2; lidx = c0 + 2; }
            if (x3 > lmax) { lmax = x3; lidx = c0 + 3; }
            if (tf == f) {
                const int t = target & 3;
                xt = (t == 0) ? x0 : (t == 1) ? x1 : (t == 2) ? x2 : x3;
            }
        }

        // --- wave-reduce (max, idx), tie -> smaller index (matches jnp.argmax)
        #pragma unroll
        for (int off = 32; off; off >>= 1) {
            const float om = __shfl_xor(lmax, off);
            const int   oi = __shfl_xor(lidx, off);
            if (om > lmax || (om == lmax && oi < lidx)) { lmax = om; lidx = oi; }
        }

        // --- sum of exp(x - max); masked comps are -INF -> exp gives 0
        float s = 0.0f;
        #pragma unroll
        for (int k = 0; k < 4; ++k) {
            s += __expf(v[k].x - lmax) + __expf(v[k].y - lmax)
               + __expf(v[k].z - lmax) + __expf(v[k].w - lmax);
        }
        #pragma unroll
        for (int off = 32; off; off >>= 1) s += __shfl_xor(s, off);

        // --- broadcast target logit from its owning lane
        xt = __shfl(xt, tf & 63);

        const float logp_t = xt - lmax - __logf(s);
        const float ce = -logp_t;
        const float pt = __expf(logp_t);
        const int pred = lidx;

        const size_t ofs = (size_t)target * NC + (size_t)pred;
        const bool lm = bfmt ? (linkb[ofs] != 0) : (linki[ofs] != 0);
        const bool hb = bfmt ? (hasb[target] != 0) : (hasi[target] != 0);
        const float w = (lm && hb && (pred != target)) ? ALPHA_LINK : 1.0f;

        const float ompt = 1.0f - pt;
        wsum += w * ompt * ompt * ce;
    }

    // all lanes of a wave hold the same wsum after the butterflies
    __shared__ float wpart[4];
    if (lane == 0) wpart[wid] = wsum;
    __syncthreads();
    if (threadIdx.x == 0)
        partial[blockIdx.x] = wpart[0] + wpart[1] + wpart[2] + wpart[3];
}

// ---- final deterministic reduction -----------------------------------------
__global__ __launch_bounds__(256) void lfl_final(const float* __restrict__ partial,
                                                 float* __restrict__ out) {
    __shared__ float sm[256];
    float s = 0.0f;
    for (int i = threadIdx.x; i < NBLOCKS; i += 256) s += partial[i];
    sm[threadIdx.x] = s;
    __syncthreads();
    for (int stride = 128; stride; stride >>= 1) {
        if ((int)threadIdx.x < stride) sm[threadIdx.x] += sm[threadIdx.x + stride];
        __syncthreads();
    }
    if (threadIdx.x == 0) out[0] = sm[0] * (1.0f / (float)NROWS);
}

extern "C" void kernel_launch(void* const* d_in, const int* in_sizes, int n_in,
                              void* d_out, int out_size, void* d_ws, size_t ws_size,
                              hipStream_t stream) {
    const float* yp = (const float*)d_in[0];
    const int*   yt = (const int*)d_in[1];
    const void*  lk = d_in[2];
    const void*  hl = d_in[3];

    float* partial = (float*)d_ws;                 // NBLOCKS floats (32 KB)
    int*   flags   = (int*)d_ws + NBLOCKS;         // 2 ints

    lfl_detect<<<1, 64, 0, stream>>>(yt, (const unsigned int*)hl, flags);
    lfl_main<<<NBLOCKS, 256, 0, stream>>>(
        yp, yt,
        (const unsigned char*)lk, (const int*)lk,
        (const unsigned char*)hl, (const int*)hl,
        flags, partial);
    lfl_final<<<1, 256, 0, stream>>>(partial, (float*)d_out);
}